// Round 4
// baseline (687.408 us; speedup 1.0000x reference)
//
#include <hip/hip_runtime.h>

#define TOK 64
#define DIMS 256
#define NHEAD 8
#define HDIM 32

typedef __attribute__((ext_vector_type(8))) short short8;
typedef __attribute__((ext_vector_type(4))) float floatx4;
typedef __attribute__((ext_vector_type(2))) unsigned int uintx2;

__device__ __forceinline__ unsigned short f2bf(float f) {
  unsigned int u = __float_as_uint(f);
  u += 0x7fffu + ((u >> 16) & 1u);   // round-to-nearest-even
  return (unsigned short)(u >> 16);
}

// ---- prep: W->bf16 (scale folded into Wq/bq), rel_bias gather transposed [h][j][i]
__global__ void prep_w(const float* __restrict__ wq, const float* __restrict__ bq,
                       const float* __restrict__ wk, const float* __restrict__ bk,
                       const float* __restrict__ wv, const float* __restrict__ bv,
                       const float* __restrict__ bias_table, const int* __restrict__ rel_index,
                       unsigned short* __restrict__ Wqkv, float* __restrict__ bias,
                       float* __restrict__ rbT) {
  const int o = blockIdx.x;      // 0..767  (output feature row of [768][256])
  const int t = threadIdx.x;     // 0..255
  const float scale = 0.17677669529663687f;  // 1/sqrt(32)
  const float* src; float s;
  if (o < 256)      { src = wq + o * 256;         s = scale; }
  else if (o < 512) { src = wk + (o - 256) * 256; s = 1.0f; }
  else              { src = wv + (o - 512) * 256; s = 1.0f; }
  Wqkv[o * 256 + t] = f2bf(src[t] * s);
  if (o == 0)      bias[t]       = bq[t] * scale;
  else if (o == 1) bias[256 + t] = bk[t];
  else if (o == 2) bias[512 + t] = bv[t];
  if (o < 128) {
    int idx = o * 256 + t;            // = h*4096 + j*64 + i
    int h = idx >> 12, j = (idx >> 6) & 63, i = idx & 63;
    rbT[idx] = bias_table[rel_index[i * 64 + j] * 8 + h];
  }
}

// ---- prep: transpose mask to [w][j][i] so epilogue loads are float4
__global__ void prep_mask(const float* __restrict__ mask, float* __restrict__ maskT) {
  int idx = blockIdx.x * 256 + threadIdx.x;  // = w*4096 + j*64 + i
  int w = idx >> 12, j = (idx >> 6) & 63, i = idx & 63;
  maskT[idx] = mask[(w << 12) + (i << 6) + j];
}

// ---- fused QKV projection + windowed attention. One block per window.
// LDS = exactly 80 KiB -> 2 blocks/CU. Occupancy is gated by COMBINED
// arch+acc VGPRs <= 256 (R2: 224 arch + acc > 256 -> 1 wave/SIMD).
// launch_bounds(256,2) budgets 256 combined; the GEMM is split into two
// row-passes (acc[6][2]=48 regs, not 96) so the budget holds w/o spill
// (R1: same bound at ~170 live regs spilled 600 B/thread = +650 MB HBM).
// After sA staging every LDS buffer is wave-private -> NO barriers in the
// main body; the 4 waves drift across GEMM/attn/PV phases for latency hiding.
__global__ __launch_bounds__(256, 2)
void attn_fused(const float* __restrict__ hidden, const unsigned short* __restrict__ Wqkv,
                const float* __restrict__ bias, const float* __restrict__ rbT,
                const float* __restrict__ maskT, float* __restrict__ out) {
  // [0..16383]            sA   [64 tok][256 feat] bf16, swz: col ^= (tok&7)<<3
  // per wave (6144 shorts @ 16384 + wave*6144):
  //   [0..2047]   sQ [64 tok][32 f]  swz: f ^= ((tok>>1)&3)<<3
  //   [2048..4095] sK same layout
  //   [4096..6143] sV [32 f][64 tok] swz: tok ^= (f&7)<<3
  //   sP = sQ..sK (64x64, overlays after Q/K dead): j ^= (i&7)<<3
  __shared__ __align__(16) unsigned short smem[40960];   // 81920 B

  const int b    = blockIdx.x;
  const int t    = threadIdx.x;
  const int wave = t >> 6;
  const int lane = t & 63;
  const int quad = lane >> 4;
  const int l16  = lane & 15;

  unsigned short* sA = smem;
  unsigned short* sQ = smem + 16384 + wave * 6144;
  unsigned short* sK = sQ + 2048;
  unsigned short* sV = sK + 2048;
  unsigned short* sP = sQ;

  // ---------- stage hidden -> sA (bf16, swizzled, stride 256)
  {
    const float* hsrc = hidden + (size_t)b * (TOK * DIMS);
    #pragma unroll
    for (int it = 0; it < 16; ++it) {
      int e = (it * 256 + t) * 4;
      int row = e >> 8, col = e & 255;
      floatx4 v = *(const floatx4*)(hsrc + e);
      union { unsigned short s[4]; uintx2 u; } pk;
      pk.s[0] = f2bf(v.x); pk.s[1] = f2bf(v.y);
      pk.s[2] = f2bf(v.z); pk.s[3] = f2bf(v.w);
      *(uintx2*)&sA[row * 256 + (col ^ ((row & 7) << 3))] = pk.u;
    }
  }
  __syncthreads();   // the ONLY barrier: sA is read-shared, all else wave-private

  const int wmod = b & 63;
  const float* mw = maskT + wmod * 4096;

  #pragma unroll 1
  for (int rep = 0; rep < 2; ++rep) {
    const int h = wave * 2 + rep;

    // ---------- QKV GEMM for head h: 96 cols = Q_h(32)|K_h(32)|V_h(32),
    // two row-passes of 32 tokens each (halves accumulator pressure).
    #pragma unroll 1
    for (int mp = 0; mp < 2; ++mp) {
      floatx4 acc[6][2];
      #pragma unroll
      for (int nt = 0; nt < 6; ++nt)
        #pragma unroll
        for (int mt = 0; mt < 2; ++mt)
          acc[nt][mt] = (floatx4){0.f, 0.f, 0.f, 0.f};
      const int aswz = (l16 & 7) << 3;
      #pragma unroll
      for (int kk = 0; kk < 8; ++kk) {
        const int koff = kk * 32 + quad * 8;
        short8 af[2];
        #pragma unroll
        for (int mt = 0; mt < 2; ++mt)
          af[mt] = *(const short8*)&sA[(mp * 32 + mt * 16 + l16) * 256 + (koff ^ aswz)];
        #pragma unroll
        for (int nt = 0; nt < 6; ++nt) {
          const int wrow = (nt >> 1) * 256 + h * 32 + (nt & 1) * 16 + l16;
          const short8 wf = *(const short8*)(Wqkv + wrow * 256 + koff);
          #pragma unroll
          for (int mt = 0; mt < 2; ++mt)
            acc[nt][mt] = __builtin_amdgcn_mfma_f32_16x16x32_bf16(af[mt], wf, acc[nt][mt], 0, 0, 0);
        }
      }
      // epilogue: +bias, cvt bf16, scatter to wave-private Q/K/V
      #pragma unroll
      for (int nt = 0; nt < 6; ++nt) {
        const int region = nt >> 1;               // 0=Q 1=K 2=V (compile-time)
        const int fc = (nt & 1) * 16 + l16;       // feature within head, 0..31
        const float bo = bias[region * 256 + h * 32 + fc];
        #pragma unroll
        for (int mt = 0; mt < 2; ++mt) {
          const int row0 = mp * 32 + mt * 16 + quad * 4;
          if (region == 2) {
            union { unsigned short s[4]; uintx2 u; } pk;
            #pragma unroll
            for (int r = 0; r < 4; ++r) pk.s[r] = f2bf(acc[nt][mt][r] + bo);
            *(uintx2*)&sV[fc * 64 + (row0 ^ ((fc & 7) << 3))] = pk.u;  // transposed
          } else {
            unsigned short* dst = region ? sK : sQ;
            #pragma unroll
            for (int r = 0; r < 4; ++r) {
              const int row = row0 + r;
              dst[row * 32 + (fc ^ (((row >> 1) & 3) << 3))] = f2bf(acc[nt][mt][r] + bo);
            }
          }
        }
      }
    }

    // ---------- S = Q_h K_h^T  (scale folded into Q); wave-private, no barrier
    floatx4 sacc[4][4];
    #pragma unroll
    for (int mt = 0; mt < 4; ++mt)
      #pragma unroll
      for (int nt = 0; nt < 4; ++nt)
        sacc[mt][nt] = (floatx4){0.f, 0.f, 0.f, 0.f};
    short8 qf[4];
    #pragma unroll
    for (int mt = 0; mt < 4; ++mt) {
      const int tok = mt * 16 + l16;
      qf[mt] = *(const short8*)&sQ[tok * 32 + ((quad * 8) ^ (((tok >> 1) & 3) << 3))];
    }
    #pragma unroll
    for (int nt = 0; nt < 4; ++nt) {
      const int tok = nt * 16 + l16;
      const short8 kf = *(const short8*)&sK[tok * 32 + ((quad * 8) ^ (((tok >> 1) & 3) << 3))];
      #pragma unroll
      for (int mt = 0; mt < 4; ++mt)
        sacc[mt][nt] = __builtin_amdgcn_mfma_f32_16x16x32_bf16(qf[mt], kf, sacc[mt][nt], 0, 0, 0);
    }
    // + rel_bias + mask (both stored [.][j][i] -> float4 over the 4 C-regs)
    const float* rb = rbT + h * 4096;
    #pragma unroll
    for (int mt = 0; mt < 4; ++mt) {
      const int i0 = mt * 16 + quad * 4;
      #pragma unroll
      for (int nt = 0; nt < 4; ++nt) {
        const int j = nt * 16 + l16;
        floatx4 rv = *(const floatx4*)(rb + j * 64 + i0);
        floatx4 mv = *(const floatx4*)(mw + j * 64 + i0);
        sacc[mt][nt] += rv + mv;
      }
    }
    // softmax over j: row r=quad*4+reg lives in the 16 lanes of this quad
    #pragma unroll
    for (int mt = 0; mt < 4; ++mt) {
      #pragma unroll
      for (int r = 0; r < 4; ++r) {
        float v0 = sacc[mt][0][r], v1 = sacc[mt][1][r];
        float v2 = sacc[mt][2][r], v3 = sacc[mt][3][r];
        float mx = fmaxf(fmaxf(v0, v1), fmaxf(v2, v3));
        mx = fmaxf(mx, __shfl_xor(mx, 1));
        mx = fmaxf(mx, __shfl_xor(mx, 2));
        mx = fmaxf(mx, __shfl_xor(mx, 4));
        mx = fmaxf(mx, __shfl_xor(mx, 8));
        float e0 = __expf(v0 - mx), e1 = __expf(v1 - mx);
        float e2 = __expf(v2 - mx), e3 = __expf(v3 - mx);
        float sm = (e0 + e1) + (e2 + e3);
        sm += __shfl_xor(sm, 1);
        sm += __shfl_xor(sm, 2);
        sm += __shfl_xor(sm, 4);
        sm += __shfl_xor(sm, 8);
        const float inv = __builtin_amdgcn_rcpf(sm);
        sacc[mt][0][r] = e0 * inv; sacc[mt][1][r] = e1 * inv;
        sacc[mt][2][r] = e2 * inv; sacc[mt][3][r] = e3 * inv;
      }
    }
    // P -> wave-private LDS (overlays dead Q+K; all qf/kf reads are done), swizzled
    #pragma unroll
    for (int mt = 0; mt < 4; ++mt) {
      const int i0 = mt * 16 + quad * 4;
      #pragma unroll
      for (int nt = 0; nt < 4; ++nt) {
        const int j = nt * 16 + l16;
        #pragma unroll
        for (int r = 0; r < 4; ++r) {
          const int i = i0 + r;
          sP[i * 64 + (j ^ ((i & 7) << 3))] = f2bf(sacc[mt][nt][r]);
        }
      }
    }

    // ---------- ctx = P x V_h  [64 x 32]  (wave-private, no barrier)
    floatx4 cacc[4][2];
    #pragma unroll
    for (int mt = 0; mt < 4; ++mt) {
      cacc[mt][0] = (floatx4){0.f, 0.f, 0.f, 0.f};
      cacc[mt][1] = (floatx4){0.f, 0.f, 0.f, 0.f};
    }
    #pragma unroll
    for (int kk = 0; kk < 2; ++kk) {
      const int joff = kk * 32 + quad * 8;
      short8 pf[4];
      #pragma unroll
      for (int mt = 0; mt < 4; ++mt) {
        const int i = mt * 16 + l16;
        pf[mt] = *(const short8*)&sP[i * 64 + (joff ^ ((i & 7) << 3))];
      }
      #pragma unroll
      for (int dt = 0; dt < 2; ++dt) {
        const int feat = dt * 16 + l16;
        const short8 vf = *(const short8*)&sV[feat * 64 + (joff ^ ((feat & 7) << 3))];
        #pragma unroll
        for (int mt = 0; mt < 4; ++mt)
          cacc[mt][dt] = __builtin_amdgcn_mfma_f32_16x16x32_bf16(pf[mt], vf, cacc[mt][dt], 0, 0, 0);
      }
    }
    // store ctx (fp32)
    float* ob = out + (size_t)b * (TOK * DIMS) + h * 32;
    #pragma unroll
    for (int mt = 0; mt < 4; ++mt) {
      const int i0 = mt * 16 + quad * 4;
      #pragma unroll
      for (int dt = 0; dt < 2; ++dt) {
        #pragma unroll
        for (int r = 0; r < 4; ++r)
          ob[(i0 + r) * 256 + dt * 16 + l16] = cacc[mt][dt][r];
      }
    }
    // no barrier: next rep's GEMM scatter only touches this wave's buffers
  }
}

extern "C" void kernel_launch(void* const* d_in, const int* in_sizes, int n_in,
                              void* d_out, int out_size, void* d_ws, size_t ws_size,
                              hipStream_t stream) {
  const float* hidden = (const float*)d_in[0];
  const float* mask   = (const float*)d_in[1];
  const float* wq = (const float*)d_in[2];
  const float* bq = (const float*)d_in[3];
  const float* wk = (const float*)d_in[4];
  const float* bk = (const float*)d_in[5];
  const float* wv = (const float*)d_in[6];
  const float* bv = (const float*)d_in[7];
  const float* bias_table = (const float*)d_in[8];
  const int*   rel_index  = (const int*)d_in[9];

  char* ws = (char*)d_ws;
  unsigned short* Wqkv = (unsigned short*)ws;               // 393216 B
  float* bias  = (float*)(ws + 393216);                     //   3072 B
  float* rbT   = (float*)(ws + 393216 + 3072);              // 131072 B
  float* maskT = (float*)(ws + 393216 + 3072 + 131072);     // 1048576 B

  prep_w<<<768, 256, 0, stream>>>(wq, bq, wk, bk, wv, bv, bias_table, rel_index,
                                  Wqkv, bias, rbT);
  prep_mask<<<1024, 256, 0, stream>>>(mask, maskT);
  attn_fused<<<2048, 256, 0, stream>>>(hidden, Wqkv, bias, rbT, maskT, (float*)d_out);
}

// Round 5
// 457.210 us; speedup vs baseline: 1.5035x; 1.5035x over previous
//
#include <hip/hip_runtime.h>

#define TOK 64
#define DIMS 256
#define NHEAD 8
#define HDIM 32

typedef __attribute__((ext_vector_type(8))) short short8;
typedef __attribute__((ext_vector_type(4))) float floatx4;
typedef __attribute__((ext_vector_type(2))) unsigned int uintx2;

__device__ __forceinline__ unsigned short f2bf(float f) {
  unsigned int u = __float_as_uint(f);
  u += 0x7fffu + ((u >> 16) & 1u);   // round-to-nearest-even
  return (unsigned short)(u >> 16);
}

// ---- prep: W->bf16 (scale folded into Wq/bq), rel_bias gather transposed [h][j][i]
__global__ void prep_w(const float* __restrict__ wq, const float* __restrict__ bq,
                       const float* __restrict__ wk, const float* __restrict__ bk,
                       const float* __restrict__ wv, const float* __restrict__ bv,
                       const float* __restrict__ bias_table, const int* __restrict__ rel_index,
                       unsigned short* __restrict__ Wqkv, float* __restrict__ bias,
                       float* __restrict__ rbT) {
  const int o = blockIdx.x;      // 0..767  (output feature row of [768][256])
  const int t = threadIdx.x;     // 0..255
  const float scale = 0.17677669529663687f;  // 1/sqrt(32)
  const float* src; float s;
  if (o < 256)      { src = wq + o * 256;         s = scale; }
  else if (o < 512) { src = wk + (o - 256) * 256; s = 1.0f; }
  else              { src = wv + (o - 512) * 256; s = 1.0f; }
  Wqkv[o * 256 + t] = f2bf(src[t] * s);
  if (o == 0)      bias[t]       = bq[t] * scale;
  else if (o == 1) bias[256 + t] = bk[t];
  else if (o == 2) bias[512 + t] = bv[t];
  if (o < 128) {
    int idx = o * 256 + t;            // = h*4096 + j*64 + i
    int h = idx >> 12, j = (idx >> 6) & 63, i = idx & 63;
    rbT[idx] = bias_table[rel_index[i * 64 + j] * 8 + h];
  }
}

// ---- prep: transpose mask to [w][j][i] so epilogue loads are float4
__global__ void prep_mask(const float* __restrict__ mask, float* __restrict__ maskT) {
  int idx = blockIdx.x * 256 + threadIdx.x;  // = w*4096 + j*64 + i
  int w = idx >> 12, j = (idx >> 6) & 63, i = idx & 63;
  maskT[idx] = mask[(w << 12) + (i << 6) + j];
}

// ---- fused QKV projection + windowed attention. One block per window.
// LDS = exactly 80 KiB -> 2 blocks/CU. Occupancy gate: ARCH-side VGPRs must
// fit the (256,2) 128-arch budget WITHOUT spilling (R1/R4 spilled 600-1100
// B/thread: full-width softmax pulled 64 AGPR accs + temps into arch regs).
// Fix: GEMM keeps wide acc[6][4] (lives in AGPRs, arch side ~50 regs);
// ATTENTION runs in two 32-row half-passes (sacc[2][4]=32, cacc[2][2]=16,
// arch live ~70). qf[4] hoisted so Q is dead before P overlays its region;
// K region stays intact across both half-passes.
// After sA staging every LDS buffer is wave-private -> no barriers in body.
__global__ __launch_bounds__(256, 2)
void attn_fused(const float* __restrict__ hidden, const unsigned short* __restrict__ Wqkv,
                const float* __restrict__ bias, const float* __restrict__ rbT,
                const float* __restrict__ maskT, float* __restrict__ out) {
  // [0..16383]            sA   [64 tok][256 feat] bf16, swz: col ^= (tok&7)<<3
  // per wave (6144 shorts @ 16384 + wave*6144):
  //   [0..2047]    sQ [64 tok][32 f]  swz: f ^= ((tok>>1)&3)<<3
  //   [2048..4095] sK same layout
  //   [4096..6143] sV [32 f][64 tok] swz: tok ^= (f&7)<<3
  //   sP = sQ region only (32 local rows x 64, per half-pass): j ^= (il&7)<<3
  __shared__ __align__(16) unsigned short smem[40960];   // 81920 B

  const int b    = blockIdx.x;
  const int t    = threadIdx.x;
  const int wave = t >> 6;
  const int lane = t & 63;
  const int quad = lane >> 4;
  const int l16  = lane & 15;

  unsigned short* sA = smem;
  unsigned short* sQ = smem + 16384 + wave * 6144;
  unsigned short* sK = sQ + 2048;
  unsigned short* sV = sK + 2048;
  unsigned short* sP = sQ;   // 32x64 per half-pass; Q is register-hoisted first

  // ---------- stage hidden -> sA (bf16, swizzled, stride 256)
  {
    const float* hsrc = hidden + (size_t)b * (TOK * DIMS);
    #pragma unroll
    for (int it = 0; it < 16; ++it) {
      int e = (it * 256 + t) * 4;
      int row = e >> 8, col = e & 255;
      floatx4 v = *(const floatx4*)(hsrc + e);
      union { unsigned short s[4]; uintx2 u; } pk;
      pk.s[0] = f2bf(v.x); pk.s[1] = f2bf(v.y);
      pk.s[2] = f2bf(v.z); pk.s[3] = f2bf(v.w);
      *(uintx2*)&sA[row * 256 + (col ^ ((row & 7) << 3))] = pk.u;
    }
  }
  __syncthreads();   // the ONLY barrier: sA is read-shared, all else wave-private

  const int wmod = b & 63;
  const float* mw = maskT + wmod * 4096;

  #pragma unroll 1
  for (int rep = 0; rep < 2; ++rep) {
    const int h = wave * 2 + rep;

    // ---------- QKV GEMM for head h: 96 cols = Q_h(32)|K_h(32)|V_h(32),
    // single pass over all 64 rows; acc[6][4] lives in AGPRs.
    {
      floatx4 acc[6][4];
      #pragma unroll
      for (int nt = 0; nt < 6; ++nt)
        #pragma unroll
        for (int mt = 0; mt < 4; ++mt)
          acc[nt][mt] = (floatx4){0.f, 0.f, 0.f, 0.f};
      const int aswz = (l16 & 7) << 3;
      #pragma unroll
      for (int kk = 0; kk < 8; ++kk) {
        const int koff = kk * 32 + quad * 8;
        short8 af[4];
        #pragma unroll
        for (int mt = 0; mt < 4; ++mt)
          af[mt] = *(const short8*)&sA[(mt * 16 + l16) * 256 + (koff ^ aswz)];
        #pragma unroll
        for (int nt = 0; nt < 6; ++nt) {
          const int wrow = (nt >> 1) * 256 + h * 32 + (nt & 1) * 16 + l16;
          const short8 wf = *(const short8*)(Wqkv + wrow * 256 + koff);
          #pragma unroll
          for (int mt = 0; mt < 4; ++mt)
            acc[nt][mt] = __builtin_amdgcn_mfma_f32_16x16x32_bf16(af[mt], wf, acc[nt][mt], 0, 0, 0);
        }
      }
      // epilogue: +bias, cvt bf16, scatter to wave-private Q/K/V
      #pragma unroll
      for (int nt = 0; nt < 6; ++nt) {
        const int region = nt >> 1;               // 0=Q 1=K 2=V (compile-time)
        const int fc = (nt & 1) * 16 + l16;       // feature within head, 0..31
        const float bo = bias[region * 256 + h * 32 + fc];
        #pragma unroll
        for (int mt = 0; mt < 4; ++mt) {
          const int row0 = mt * 16 + quad * 4;
          if (region == 2) {
            union { unsigned short s[4]; uintx2 u; } pk;
            #pragma unroll
            for (int r = 0; r < 4; ++r) pk.s[r] = f2bf(acc[nt][mt][r] + bo);
            *(uintx2*)&sV[fc * 64 + (row0 ^ ((fc & 7) << 3))] = pk.u;  // transposed
          } else {
            unsigned short* dst = region ? sK : sQ;
            #pragma unroll
            for (int r = 0; r < 4; ++r) {
              const int row = row0 + r;
              dst[row * 32 + (fc ^ (((row >> 1) & 3) << 3))] = f2bf(acc[nt][mt][r] + bo);
            }
          }
        }
      }
    }

    // ---------- hoist all Q fragments (Q dead afterwards; P may overlay sQ)
    short8 qf[4];
    #pragma unroll
    for (int mt = 0; mt < 4; ++mt) {
      const int tok = mt * 16 + l16;
      qf[mt] = *(const short8*)&sQ[tok * 32 + ((quad * 8) ^ (((tok >> 1) & 3) << 3))];
    }

    // ---------- attention in two 32-row half-passes (halves arch reg pressure)
    #pragma unroll 1
    for (int hp = 0; hp < 2; ++hp) {
      // S-half = Q[hp] K^T
      floatx4 sacc[2][4];
      #pragma unroll
      for (int mt = 0; mt < 2; ++mt)
        #pragma unroll
        for (int nt = 0; nt < 4; ++nt)
          sacc[mt][nt] = (floatx4){0.f, 0.f, 0.f, 0.f};
      #pragma unroll
      for (int nt = 0; nt < 4; ++nt) {
        const int tok = nt * 16 + l16;
        const short8 kf = *(const short8*)&sK[tok * 32 + ((quad * 8) ^ (((tok >> 1) & 3) << 3))];
        #pragma unroll
        for (int mt = 0; mt < 2; ++mt)
          sacc[mt][nt] = __builtin_amdgcn_mfma_f32_16x16x32_bf16(qf[hp * 2 + mt], kf, sacc[mt][nt], 0, 0, 0);
      }
      // + rel_bias + mask (both stored [.][j][i] -> float4 over the 4 C-regs)
      const float* rb = rbT + h * 4096;
      #pragma unroll
      for (int mt = 0; mt < 2; ++mt) {
        const int i0 = hp * 32 + mt * 16 + quad * 4;
        #pragma unroll
        for (int nt = 0; nt < 4; ++nt) {
          const int j = nt * 16 + l16;
          floatx4 rv = *(const floatx4*)(rb + j * 64 + i0);
          floatx4 mv = *(const floatx4*)(mw + j * 64 + i0);
          sacc[mt][nt] += rv + mv;
        }
      }
      // softmax over j: row r=quad*4+reg lives in the 16 lanes of this quad
      #pragma unroll
      for (int mt = 0; mt < 2; ++mt) {
        #pragma unroll
        for (int r = 0; r < 4; ++r) {
          float v0 = sacc[mt][0][r], v1 = sacc[mt][1][r];
          float v2 = sacc[mt][2][r], v3 = sacc[mt][3][r];
          float mx = fmaxf(fmaxf(v0, v1), fmaxf(v2, v3));
          mx = fmaxf(mx, __shfl_xor(mx, 1));
          mx = fmaxf(mx, __shfl_xor(mx, 2));
          mx = fmaxf(mx, __shfl_xor(mx, 4));
          mx = fmaxf(mx, __shfl_xor(mx, 8));
          float e0 = __expf(v0 - mx), e1 = __expf(v1 - mx);
          float e2 = __expf(v2 - mx), e3 = __expf(v3 - mx);
          float sm = (e0 + e1) + (e2 + e3);
          sm += __shfl_xor(sm, 1);
          sm += __shfl_xor(sm, 2);
          sm += __shfl_xor(sm, 4);
          sm += __shfl_xor(sm, 8);
          const float inv = __builtin_amdgcn_rcpf(sm);
          sacc[mt][0][r] = e0 * inv; sacc[mt][1][r] = e1 * inv;
          sacc[mt][2][r] = e2 * inv; sacc[mt][3][r] = e3 * inv;
        }
      }
      // P-half -> sP (local rows 0..31 in the freed sQ region), swizzled
      #pragma unroll
      for (int mt = 0; mt < 2; ++mt) {
        const int il0 = mt * 16 + quad * 4;
        #pragma unroll
        for (int nt = 0; nt < 4; ++nt) {
          const int j = nt * 16 + l16;
          #pragma unroll
          for (int r = 0; r < 4; ++r) {
            const int il = il0 + r;
            sP[il * 64 + (j ^ ((il & 7) << 3))] = f2bf(sacc[mt][nt][r]);
          }
        }
      }

      // ctx-half = P_half x V_h  [32 x 32]
      floatx4 cacc[2][2];
      #pragma unroll
      for (int mt = 0; mt < 2; ++mt) {
        cacc[mt][0] = (floatx4){0.f, 0.f, 0.f, 0.f};
        cacc[mt][1] = (floatx4){0.f, 0.f, 0.f, 0.f};
      }
      #pragma unroll
      for (int kk = 0; kk < 2; ++kk) {
        const int joff = kk * 32 + quad * 8;
        short8 pf[2];
        #pragma unroll
        for (int mt = 0; mt < 2; ++mt) {
          const int il = mt * 16 + l16;
          pf[mt] = *(const short8*)&sP[il * 64 + (joff ^ ((il & 7) << 3))];
        }
        #pragma unroll
        for (int dt = 0; dt < 2; ++dt) {
          const int feat = dt * 16 + l16;
          const short8 vf = *(const short8*)&sV[feat * 64 + (joff ^ ((feat & 7) << 3))];
          #pragma unroll
          for (int mt = 0; mt < 2; ++mt)
            cacc[mt][dt] = __builtin_amdgcn_mfma_f32_16x16x32_bf16(pf[mt], vf, cacc[mt][dt], 0, 0, 0);
        }
      }
      // store ctx-half (fp32)
      float* ob = out + (size_t)b * (TOK * DIMS) + h * 32;
      #pragma unroll
      for (int mt = 0; mt < 2; ++mt) {
        const int i0 = hp * 32 + mt * 16 + quad * 4;
        #pragma unroll
        for (int dt = 0; dt < 2; ++dt) {
          #pragma unroll
          for (int r = 0; r < 4; ++r)
            ob[(i0 + r) * 256 + dt * 16 + l16] = cacc[mt][dt][r];
        }
      }
    }
    // no barrier: next rep's GEMM scatter only touches this wave's buffers
  }
}

extern "C" void kernel_launch(void* const* d_in, const int* in_sizes, int n_in,
                              void* d_out, int out_size, void* d_ws, size_t ws_size,
                              hipStream_t stream) {
  const float* hidden = (const float*)d_in[0];
  const float* mask   = (const float*)d_in[1];
  const float* wq = (const float*)d_in[2];
  const float* bq = (const float*)d_in[3];
  const float* wk = (const float*)d_in[4];
  const float* bk = (const float*)d_in[5];
  const float* wv = (const float*)d_in[6];
  const float* bv = (const float*)d_in[7];
  const float* bias_table = (const float*)d_in[8];
  const int*   rel_index  = (const int*)d_in[9];

  char* ws = (char*)d_ws;
  unsigned short* Wqkv = (unsigned short*)ws;               // 393216 B
  float* bias  = (float*)(ws + 393216);                     //   3072 B
  float* rbT   = (float*)(ws + 393216 + 3072);              // 131072 B
  float* maskT = (float*)(ws + 393216 + 3072 + 131072);     // 1048576 B

  prep_w<<<768, 256, 0, stream>>>(wq, bq, wk, bk, wv, bv, bias_table, rel_index,
                                  Wqkv, bias, rbT);
  prep_mask<<<1024, 256, 0, stream>>>(mask, maskT);
  attn_fused<<<2048, 256, 0, stream>>>(hidden, Wqkv, bias, rbT, maskT, (float*)d_out);
}

// Round 7
// 392.220 us; speedup vs baseline: 1.7526x; 1.1657x over previous
//
#include <hip/hip_runtime.h>

#define TOK 64
#define DIMS 256
#define NHEAD 8
#define HDIM 32

typedef __attribute__((ext_vector_type(8))) short short8;
typedef __attribute__((ext_vector_type(4))) float floatx4;
typedef __attribute__((ext_vector_type(2))) unsigned int uintx2;

__device__ __forceinline__ unsigned short f2bf(float f) {
  unsigned int u = __float_as_uint(f);
  u += 0x7fffu + ((u >> 16) & 1u);   // round-to-nearest-even
  return (unsigned short)(u >> 16);
}

// ---- prep: W->bf16 (scale folded into Wq/bq), rel_bias gather transposed [h][j][i]
__global__ void prep_w(const float* __restrict__ wq, const float* __restrict__ bq,
                       const float* __restrict__ wk, const float* __restrict__ bk,
                       const float* __restrict__ wv, const float* __restrict__ bv,
                       const float* __restrict__ bias_table, const int* __restrict__ rel_index,
                       unsigned short* __restrict__ Wqkv, float* __restrict__ bias,
                       float* __restrict__ rbT) {
  const int o = blockIdx.x;      // 0..767  (output feature row of [768][256])
  const int t = threadIdx.x;     // 0..255
  const float scale = 0.17677669529663687f;  // 1/sqrt(32)
  const float* src; float s;
  if (o < 256)      { src = wq + o * 256;         s = scale; }
  else if (o < 512) { src = wk + (o - 256) * 256; s = 1.0f; }
  else              { src = wv + (o - 512) * 256; s = 1.0f; }
  Wqkv[o * 256 + t] = f2bf(src[t] * s);
  if (o == 0)      bias[t]       = bq[t] * scale;
  else if (o == 1) bias[256 + t] = bk[t];
  else if (o == 2) bias[512 + t] = bv[t];
  if (o < 128) {
    int idx = o * 256 + t;            // = h*4096 + j*64 + i
    int h = idx >> 12, j = (idx >> 6) & 63, i = idx & 63;
    rbT[idx] = bias_table[rel_index[i * 64 + j] * 8 + h];
  }
}

// ---- prep: transpose mask to [w][j][i] so epilogue loads are float4
__global__ void prep_mask(const float* __restrict__ mask, float* __restrict__ maskT) {
  int idx = blockIdx.x * 256 + threadIdx.x;  // = w*4096 + j*64 + i
  int w = idx >> 12, j = (idx >> 6) & 63, i = idx & 63;
  maskT[idx] = mask[(w << 12) + (i << 6) + j];
}

// ---- fused QKV projection + windowed attention. One block per window.
// LDS = exactly 80 KiB -> 2 blocks/CU. Occupancy gate: ARCH-side VGPRs must
// fit the (256,2) 128-arch budget WITHOUT spilling.
// R5 lesson: full unroll of the GEMM kk-loop let the scheduler hoist up to
// 48 wf b128 loads (192 regs) -> ~300 B/thread spill (~157 MB HBM traffic).
// Fix: #pragma unroll 2 on kk caps the hoist window at 12 wf loads (~90 arch
// regs peak). GEMM acc[6][4] lives in AGPRs; attention runs in two 32-row
// half-passes (sacc[2][4], cacc[2][2]); qf[4] hoisted so P may overlay sQ.
// After sA staging every LDS buffer is wave-private -> no barriers in body.
__global__ __launch_bounds__(256, 2)
void attn_fused(const float* __restrict__ hidden, const unsigned short* __restrict__ Wqkv,
                const float* __restrict__ bias, const float* __restrict__ rbT,
                const float* __restrict__ maskT, float* __restrict__ out) {
  // [0..16383]            sA   [64 tok][256 feat] bf16, swz: col ^= (tok&7)<<3
  // per wave (6144 shorts @ 16384 + wave*6144):
  //   [0..2047]    sQ [64 tok][32 f]  swz: f ^= ((tok>>1)&3)<<3
  //   [2048..4095] sK same layout
  //   [4096..6143] sV [32 f][64 tok] swz: tok ^= (f&7)<<3
  //   sP = sQ region only (32 local rows x 64, per half-pass): j ^= (il&7)<<3
  __shared__ __align__(16) unsigned short smem[40960];   // 81920 B

  const int b    = blockIdx.x;
  const int t    = threadIdx.x;
  const int wave = t >> 6;
  const int lane = t & 63;
  const int quad = lane >> 4;
  const int l16  = lane & 15;

  unsigned short* sA = smem;
  unsigned short* sQ = smem + 16384 + wave * 6144;
  unsigned short* sK = sQ + 2048;
  unsigned short* sV = sK + 2048;
  unsigned short* sP = sQ;   // 32x64 per half-pass; Q is register-hoisted first

  // ---------- stage hidden -> sA (bf16, swizzled, stride 256)
  {
    const float* hsrc = hidden + (size_t)b * (TOK * DIMS);
    #pragma unroll
    for (int it = 0; it < 16; ++it) {
      int e = (it * 256 + t) * 4;
      int row = e >> 8, col = e & 255;
      floatx4 v = *(const floatx4*)(hsrc + e);
      union { unsigned short s[4]; uintx2 u; } pk;
      pk.s[0] = f2bf(v.x); pk.s[1] = f2bf(v.y);
      pk.s[2] = f2bf(v.z); pk.s[3] = f2bf(v.w);
      *(uintx2*)&sA[row * 256 + (col ^ ((row & 7) << 3))] = pk.u;
    }
  }
  __syncthreads();   // the ONLY barrier: sA is read-shared, all else wave-private

  const int wmod = b & 63;
  const float* mw = maskT + wmod * 4096;

  #pragma unroll 1
  for (int rep = 0; rep < 2; ++rep) {
    const int h = wave * 2 + rep;

    // ---------- QKV GEMM for head h: 96 cols = Q_h(32)|K_h(32)|V_h(32),
    // single pass over all 64 rows; acc[6][4] lives in AGPRs.
    {
      floatx4 acc[6][4];
      #pragma unroll
      for (int nt = 0; nt < 6; ++nt)
        #pragma unroll
        for (int mt = 0; mt < 4; ++mt)
          acc[nt][mt] = (floatx4){0.f, 0.f, 0.f, 0.f};
      const int aswz = (l16 & 7) << 3;
      // unroll 2 (not full): caps the scheduler's load-hoist window at
      // 12 wf loads / ~90 arch regs -> no spill under the 128-arch cap (R5).
      #pragma unroll 2
      for (int kk = 0; kk < 8; ++kk) {
        const int koff = kk * 32 + quad * 8;
        short8 af[4];
        #pragma unroll
        for (int mt = 0; mt < 4; ++mt)
          af[mt] = *(const short8*)&sA[(mt * 16 + l16) * 256 + (koff ^ aswz)];
        #pragma unroll
        for (int nt = 0; nt < 6; ++nt) {
          const int wrow = (nt >> 1) * 256 + h * 32 + (nt & 1) * 16 + l16;
          const short8 wf = *(const short8*)(Wqkv + wrow * 256 + koff);
          #pragma unroll
          for (int mt = 0; mt < 4; ++mt)
            acc[nt][mt] = __builtin_amdgcn_mfma_f32_16x16x32_bf16(af[mt], wf, acc[nt][mt], 0, 0, 0);
        }
      }
      // epilogue: +bias, cvt bf16, scatter to wave-private Q/K/V
      #pragma unroll
      for (int nt = 0; nt < 6; ++nt) {
        const int region = nt >> 1;               // 0=Q 1=K 2=V (compile-time)
        const int fc = (nt & 1) * 16 + l16;       // feature within head, 0..31
        const float bo = bias[region * 256 + h * 32 + fc];
        #pragma unroll
        for (int mt = 0; mt < 4; ++mt) {
          const int row0 = mt * 16 + quad * 4;
          if (region == 2) {
            union { unsigned short s[4]; uintx2 u; } pk;
            #pragma unroll
            for (int r = 0; r < 4; ++r) pk.s[r] = f2bf(acc[nt][mt][r] + bo);
            *(uintx2*)&sV[fc * 64 + (row0 ^ ((fc & 7) << 3))] = pk.u;  // transposed
          } else {
            unsigned short* dst = region ? sK : sQ;
            #pragma unroll
            for (int r = 0; r < 4; ++r) {
              const int row = row0 + r;
              dst[row * 32 + (fc ^ (((row >> 1) & 3) << 3))] = f2bf(acc[nt][mt][r] + bo);
            }
          }
        }
      }
    }

    // ---------- hoist all Q fragments (Q dead afterwards; P may overlay sQ)
    short8 qf[4];
    #pragma unroll
    for (int mt = 0; mt < 4; ++mt) {
      const int tok = mt * 16 + l16;
      qf[mt] = *(const short8*)&sQ[tok * 32 + ((quad * 8) ^ (((tok >> 1) & 3) << 3))];
    }

    // ---------- attention in two 32-row half-passes (halves arch reg pressure)
    #pragma unroll 1
    for (int hp = 0; hp < 2; ++hp) {
      // S-half = Q[hp] K^T
      floatx4 sacc[2][4];
      #pragma unroll
      for (int mt = 0; mt < 2; ++mt)
        #pragma unroll
        for (int nt = 0; nt < 4; ++nt)
          sacc[mt][nt] = (floatx4){0.f, 0.f, 0.f, 0.f};
      #pragma unroll
      for (int nt = 0; nt < 4; ++nt) {
        const int tok = nt * 16 + l16;
        const short8 kf = *(const short8*)&sK[tok * 32 + ((quad * 8) ^ (((tok >> 1) & 3) << 3))];
        #pragma unroll
        for (int mt = 0; mt < 2; ++mt)
          sacc[mt][nt] = __builtin_amdgcn_mfma_f32_16x16x32_bf16(qf[hp * 2 + mt], kf, sacc[mt][nt], 0, 0, 0);
      }
      // + rel_bias + mask (both stored [.][j][i] -> float4 over the 4 C-regs)
      const float* rb = rbT + h * 4096;
      #pragma unroll
      for (int mt = 0; mt < 2; ++mt) {
        const int i0 = hp * 32 + mt * 16 + quad * 4;
        #pragma unroll
        for (int nt = 0; nt < 4; ++nt) {
          const int j = nt * 16 + l16;
          floatx4 rv = *(const floatx4*)(rb + j * 64 + i0);
          floatx4 mv = *(const floatx4*)(mw + j * 64 + i0);
          sacc[mt][nt] += rv + mv;
        }
      }
      // softmax over j: row r=quad*4+reg lives in the 16 lanes of this quad
      #pragma unroll
      for (int mt = 0; mt < 2; ++mt) {
        #pragma unroll
        for (int r = 0; r < 4; ++r) {
          float v0 = sacc[mt][0][r], v1 = sacc[mt][1][r];
          float v2 = sacc[mt][2][r], v3 = sacc[mt][3][r];
          float mx = fmaxf(fmaxf(v0, v1), fmaxf(v2, v3));
          mx = fmaxf(mx, __shfl_xor(mx, 1));
          mx = fmaxf(mx, __shfl_xor(mx, 2));
          mx = fmaxf(mx, __shfl_xor(mx, 4));
          mx = fmaxf(mx, __shfl_xor(mx, 8));
          float e0 = __expf(v0 - mx), e1 = __expf(v1 - mx);
          float e2 = __expf(v2 - mx), e3 = __expf(v3 - mx);
          float sm = (e0 + e1) + (e2 + e3);
          sm += __shfl_xor(sm, 1);
          sm += __shfl_xor(sm, 2);
          sm += __shfl_xor(sm, 4);
          sm += __shfl_xor(sm, 8);
          const float inv = __builtin_amdgcn_rcpf(sm);
          sacc[mt][0][r] = e0 * inv; sacc[mt][1][r] = e1 * inv;
          sacc[mt][2][r] = e2 * inv; sacc[mt][3][r] = e3 * inv;
        }
      }
      // P-half -> sP (local rows 0..31 in the freed sQ region), swizzled
      #pragma unroll
      for (int mt = 0; mt < 2; ++mt) {
        const int il0 = mt * 16 + quad * 4;
        #pragma unroll
        for (int nt = 0; nt < 4; ++nt) {
          const int j = nt * 16 + l16;
          #pragma unroll
          for (int r = 0; r < 4; ++r) {
            const int il = il0 + r;
            sP[il * 64 + (j ^ ((il & 7) << 3))] = f2bf(sacc[mt][nt][r]);
          }
        }
      }

      // ctx-half = P_half x V_h  [32 x 32]
      floatx4 cacc[2][2];
      #pragma unroll
      for (int mt = 0; mt < 2; ++mt) {
        cacc[mt][0] = (floatx4){0.f, 0.f, 0.f, 0.f};
        cacc[mt][1] = (floatx4){0.f, 0.f, 0.f, 0.f};
      }
      #pragma unroll
      for (int kk = 0; kk < 2; ++kk) {
        const int joff = kk * 32 + quad * 8;
        short8 pf[2];
        #pragma unroll
        for (int mt = 0; mt < 2; ++mt) {
          const int il = mt * 16 + l16;
          pf[mt] = *(const short8*)&sP[il * 64 + (joff ^ ((il & 7) << 3))];
        }
        #pragma unroll
        for (int dt = 0; dt < 2; ++dt) {
          const int feat = dt * 16 + l16;
          const short8 vf = *(const short8*)&sV[feat * 64 + (joff ^ ((feat & 7) << 3))];
          #pragma unroll
          for (int mt = 0; mt < 2; ++mt)
            cacc[mt][dt] = __builtin_amdgcn_mfma_f32_16x16x32_bf16(pf[mt], vf, cacc[mt][dt], 0, 0, 0);
        }
      }
      // store ctx-half (fp32)
      float* ob = out + (size_t)b * (TOK * DIMS) + h * 32;
      #pragma unroll
      for (int mt = 0; mt < 2; ++mt) {
        const int i0 = hp * 32 + mt * 16 + quad * 4;
        #pragma unroll
        for (int dt = 0; dt < 2; ++dt) {
          #pragma unroll
          for (int r = 0; r < 4; ++r)
            ob[(i0 + r) * 256 + dt * 16 + l16] = cacc[mt][dt][r];
        }
      }
    }
    // no barrier: next rep's GEMM scatter only touches this wave's buffers
  }
}

extern "C" void kernel_launch(void* const* d_in, const int* in_sizes, int n_in,
                              void* d_out, int out_size, void* d_ws, size_t ws_size,
                              hipStream_t stream) {
  const float* hidden = (const float*)d_in[0];
  const float* mask   = (const float*)d_in[1];
  const float* wq = (const float*)d_in[2];
  const float* bq = (const float*)d_in[3];
  const float* wk = (const float*)d_in[4];
  const float* bk = (const float*)d_in[5];
  const float* wv = (const float*)d_in[6];
  const float* bv = (const float*)d_in[7];
  const float* bias_table = (const float*)d_in[8];
  const int*   rel_index  = (const int*)d_in[9];

  char* ws = (char*)d_ws;
  unsigned short* Wqkv = (unsigned short*)ws;               // 393216 B
  float* bias  = (float*)(ws + 393216);                     //   3072 B
  float* rbT   = (float*)(ws + 393216 + 3072);              // 131072 B
  float* maskT = (float*)(ws + 393216 + 3072 + 131072);     // 1048576 B

  prep_w<<<768, 256, 0, stream>>>(wq, bq, wk, bk, wv, bv, bias_table, rel_index,
                                  Wqkv, bias, rbT);
  prep_mask<<<1024, 256, 0, stream>>>(mask, maskT);
  attn_fused<<<2048, 256, 0, stream>>>(hidden, Wqkv, bias, rbT, maskT, (float*)d_out);
}